// Round 1
// baseline (843.090 us; speedup 1.0000x reference)
//
#include <hip/hip_runtime.h>

// LIF spiking layer (SpikeLayer_33122787787178)
// x: [B=64, T=8, C=256, H=32, W=32] fp32  ->  spikes, same shape, fp32 (0.0/1.0)
// Recurrence per neuron (b,c,h,w) over t:
//   mem = mem*DECAY + x_t;  spike = (mem - VTH > 0);  mem = (1-spike)*mem
// Pure streaming op: 512 MB read + 512 MB write => HBM-bound (~170 us @ 6.3 TB/s).
//
// Layout notes:
//  - time stride = C*H*W = 262144 floats; per (b,t) slice is contiguous.
//  - one thread owns 4 consecutive neurons (one float4 column), does 8 coalesced
//    float4 loads + 8 coalesced float4 stores. Loads are address-independent, so
//    the unrolled loop exposes 8-deep MLP; __restrict__ allows load/store reorder.
//  - DECAY=0.25 is a power of two => mem*DECAY is exact, FMA contraction cannot
//    perturb results vs numpy's separate mul+add. Spikes are bit-exact 0/1.

constexpr int   T_STEPS = 8;
constexpr int   CHW4    = 256 * 32 * 32 / 4;   // 65536 float4 per (b,t) slice (2^16)
constexpr float VTH     = 0.5f;
constexpr float DECAY   = 0.25f;

__global__ __launch_bounds__(256) void lif_kernel(const float4* __restrict__ x,
                                                  float4* __restrict__ out,
                                                  int n_items) {
    const int stride = gridDim.x * blockDim.x;
    for (int i = blockIdx.x * blockDim.x + threadIdx.x; i < n_items; i += stride) {
        const int b = i >> 16;               // i / CHW4
        const int n = i & (CHW4 - 1);        // i % CHW4
        const size_t base = ((size_t)b * T_STEPS) * (size_t)CHW4 + (size_t)n;

        float4 mem = make_float4(0.f, 0.f, 0.f, 0.f);
        #pragma unroll
        for (int t = 0; t < T_STEPS; ++t) {
            const float4 xi = x[base + (size_t)t * CHW4];
            float4 sp;
            mem.x = mem.x * DECAY + xi.x;  sp.x = (mem.x - VTH > 0.f) ? 1.f : 0.f;  mem.x = (1.f - sp.x) * mem.x;
            mem.y = mem.y * DECAY + xi.y;  sp.y = (mem.y - VTH > 0.f) ? 1.f : 0.f;  mem.y = (1.f - sp.y) * mem.y;
            mem.z = mem.z * DECAY + xi.z;  sp.z = (mem.z - VTH > 0.f) ? 1.f : 0.f;  mem.z = (1.f - sp.z) * mem.z;
            mem.w = mem.w * DECAY + xi.w;  sp.w = (mem.w - VTH > 0.f) ? 1.f : 0.f;  mem.w = (1.f - sp.w) * mem.w;
            out[base + (size_t)t * CHW4] = sp;
        }
    }
}

extern "C" void kernel_launch(void* const* d_in, const int* in_sizes, int n_in,
                              void* d_out, int out_size, void* d_ws, size_t ws_size,
                              hipStream_t stream) {
    const float4* x   = (const float4*)d_in[0];
    float4*       out = (float4*)d_out;
    // d_in[1] is now_T (==8, fixed by the bench; output shape already reflects it).
    const int n_items = out_size / (T_STEPS * 4);   // B * CHW4 float4 columns
    const int block   = 256;
    const int grid    = 2048;                       // grid-stride, ~8 columns/thread
    lif_kernel<<<grid, block, 0, stream>>>(x, out, n_items);
}